// Round 11
// baseline (944.156 us; speedup 1.0000x reference)
//
#include <hip/hip_runtime.h>
#include <hip/hip_bf16.h>

#define V  32000
#define HD 512
#define BB 32
#define TT 128
#define VH 32512   // V + HD
#define LBLK 8     // lstm blocks (co-XCD0, weights register-resident)
#define NBLK 256   // total co-resident blocks (1 per CU)
#define NGEMM (NBLK - LBLK - 1)   // 247 gemm workers (1 publisher)
#define NTILE (32 * 125)          // gemm tiles: 4096/128 x 32000/256

typedef short  short8  __attribute__((ext_vector_type(8)));
typedef unsigned short u16x8 __attribute__((ext_vector_type(8)));
typedef unsigned short u16x4 __attribute__((ext_vector_type(4)));
typedef float  f32x4   __attribute__((ext_vector_type(4)));

__device__ __forceinline__ unsigned short bf16_rne(float f) {
  unsigned u = __builtin_bit_cast(unsigned, f);
  u += 0x7FFFu + ((u >> 16) & 1u);
  return (unsigned short)(u >> 16);
}

__device__ __forceinline__ void gload_lds16(const void* g, void* l) {
  __builtin_amdgcn_global_load_lds((const __attribute__((address_space(1))) void*)g,
                                   (__attribute__((address_space(3))) void*)l, 16, 0, 0);
}

__device__ __forceinline__ float sigf(float x) {
  return 1.0f / (1.0f + __expf(-x));
}
__device__ __forceinline__ float tanhf_fast(float x) {
  return 1.0f - 2.0f / (1.0f + __expf(2.0f * x));
}

__device__ __forceinline__ unsigned aload(const unsigned* p) {
  return __hip_atomic_load(p, __ATOMIC_RELAXED, __HIP_MEMORY_SCOPE_AGENT);
}
__device__ __forceinline__ void astore(unsigned* p, unsigned v) {
  __hip_atomic_store(p, v, __ATOMIC_RELAXED, __HIP_MEMORY_SCOPE_AGENT);
}
__device__ __forceinline__ unsigned aadd(unsigned* p, unsigned v) {
  return __hip_atomic_fetch_add(p, v, __ATOMIC_RELAXED, __HIP_MEMORY_SCOPE_AGENT);
}

// ---------------------------------------------------------------------------
// Persistent 128x256 GEMM tile loop, dynamic tile counter. Called by gemm
// workers, the publisher (after publishing), and lstm blocks (after the
// recurrence). Gated per-tile by bar2.
// ---------------------------------------------------------------------------
__device__ __forceinline__ void run_tiles(
    char* smem, const unsigned short* Hs, const unsigned short* Wyb,
    const float* by, float* Y, unsigned* bar2, unsigned* tcount)
{
  const int tid = threadIdx.x;
  const int wid = tid >> 6, lane = tid & 63;
  const int fr = lane & 15, ko = lane >> 4;
  const int wr = wid >> 2, wc = wid & 3;   // 2 x 4 wave grid
  unsigned short* As = (unsigned short*)smem;             // 128x64
  unsigned short* Bs = (unsigned short*)(smem + 16384);   // 256x64
  int* sh_tile = (int*)(smem + 49216);

  while (true) {
    if (tid == 0) *sh_tile = (int)aadd(tcount, 1u);
    __syncthreads();
    const int tile = *sh_tile;
    if (tile >= NTILE) break;
    const int bm = tile / 125, bn = tile % 125;
    const int row0 = bm << 7, col0 = bn << 8;

    if (tid == 0) {
      const unsigned need = (unsigned)(4 * bm + 4);
      while (aload(bar2) < need)
        __builtin_amdgcn_s_sleep(2);
    }
    __syncthreads();

    f32x4 acc[4][4];
    #pragma unroll
    for (int m = 0; m < 4; ++m)
      #pragma unroll
      for (int n = 0; n < 4; ++n)
        acc[m][n] = (f32x4){0.f, 0.f, 0.f, 0.f};

    for (int kt = 0; kt < 8; ++kt) {
      const int k0 = kt << 6;
      #pragma unroll
      for (int is = 0; is < 2; ++is) {
        const int id = is * 512 + tid;
        const int r = id >> 3;
        const int c = (id & 7) ^ (r & 7);
        gload_lds16(Hs + (size_t)(row0 + r) * 512 + k0 + c * 8,
                    &As[(is * 512 + (tid & ~63)) * 8]);
      }
      #pragma unroll
      for (int is = 0; is < 4; ++is) {
        const int id = is * 512 + tid;
        const int r = id >> 3;
        const int c = (id & 7) ^ (r & 7);
        gload_lds16(Wyb + (size_t)(col0 + r) * 512 + k0 + c * 8,
                    &Bs[(is * 512 + (tid & ~63)) * 8]);
      }
      __syncthreads();
      #pragma unroll
      for (int kk = 0; kk < 2; ++kk) {
        short8 af[4], bfr[4];
        #pragma unroll
        for (int m = 0; m < 4; ++m) {
          const int r = (wr << 6) + (m << 4) + fr;
          const int c = ((kk << 2) | ko) ^ (r & 7);
          af[m] = *(const short8*)&As[r * 64 + c * 8];
        }
        #pragma unroll
        for (int n = 0; n < 4; ++n) {
          const int r = (wc << 6) + (n << 4) + fr;
          const int c = ((kk << 2) | ko) ^ (r & 7);
          bfr[n] = *(const short8*)&Bs[r * 64 + c * 8];
        }
        #pragma unroll
        for (int m = 0; m < 4; ++m)
          #pragma unroll
          for (int n = 0; n < 4; ++n)
            acc[m][n] = __builtin_amdgcn_mfma_f32_16x16x32_bf16(
                af[m], bfr[n], acc[m][n], 0, 0, 0);
      }
      __syncthreads();
    }

    const int rgrp = lane >> 4;
    #pragma unroll
    for (int n = 0; n < 4; ++n) {
      const int col = col0 + (wc << 6) + (n << 4) + fr;
      const float bias = by[col];
      #pragma unroll
      for (int m = 0; m < 4; ++m) {
        const int rowb = row0 + (wr << 6) + (m << 4) + (rgrp << 2);
        #pragma unroll
        for (int j = 0; j < 4; ++j) {
          __builtin_nontemporal_store(acc[m][n][j] + bias,
                                      &Y[(size_t)(rowb + j) * V + col]);
        }
      }
    }
  }
}

// ---------------------------------------------------------------------------
// Fused cooperative kernel: 256 blocks x 512 threads (1 per CU).
// LSTM (8 XCD0 blocks): per-wave flags; step chain = poll -> stage h ->
//   MFMA (P^T = W.h^T, A-rows q*4+gate) -> in-lane gates -> h store ->
//   vmcnt(0) (h only!) -> flag -> E[t+1] load (off-path, L3-resident).
// Publisher (1 XCD0 block): polls wave flags, __threadfence (wbl2 of shared
//   XCD0 L2) + bar2 publish every 8 steps. No fences on lstm path.
// GEMM workers (247): gather E quarters (normal stores -> L2/L3, NOT NT),
//   convert Wyb, dynamic 128x256 tiles.
// ---------------------------------------------------------------------------
__global__ void __launch_bounds__(512, 2) fused_all(
    const int* __restrict__ X,
    const float* __restrict__ Hin,
    const float* __restrict__ Cin,
    const float* __restrict__ Wf, const float* __restrict__ bfp,
    const float* __restrict__ Wi, const float* __restrict__ bip,
    const float* __restrict__ Wo, const float* __restrict__ bop,
    const float* __restrict__ Wc, const float* __restrict__ bcp,
    const float* __restrict__ Wy, const float* __restrict__ by,
    float* __restrict__ E,               // [TT][BB][HD][4] f32
    unsigned short* __restrict__ HsM1,   // slots 0..128: [129][32][512] bf16
    unsigned short* __restrict__ Wyb,    // [32000][512] bf16
    float* __restrict__ outHC,
    unsigned* __restrict__ bar2,         // progress flag (for GEMM gating)
    unsigned* __restrict__ wbar,         // Wyb-convert arrivals
    unsigned* __restrict__ tcount,       // dynamic tile counter
    unsigned* __restrict__ eflag,        // [TT] gather completion (4 each)
    unsigned* __restrict__ wflag,        // [64] per-wave flags, 64B apart
    unsigned* __restrict__ lticket,
    unsigned* __restrict__ gticket,
    float* __restrict__ Y)
{
  __shared__ __align__(16) char smem[75776];
  __shared__ int sh_role;

  const int tid = threadIdx.x;
  const int wid = tid >> 6, lane = tid & 63;
  const int fr = lane & 15, ko = lane >> 4;
  const int rowgrp = lane >> 4;

  unsigned short* Hs = HsM1 + BB * HD;   // GEMM A view: slots 1..128

  // ---- runtime role claim on XCD0: 8 lstm + 1 publisher ----
  if (tid == 0) {
    unsigned xcd;
    asm volatile("s_getreg_b32 %0, hwreg(20, 0, 32)" : "=s"(xcd));  // XCC_ID
    int role = -1;   // -1 undecided
    if (xcd == 0) {
      const unsigned s = aadd(lticket, 1u);
      if (s < (unsigned)LBLK) role = (int)s;       // lstm 0..7
      else if (s == (unsigned)LBLK) role = 100;    // publisher
    }
    if (role == -1) {
      const unsigned g = aadd(gticket, 1u);
      role = -(int)g - 2;                          // gemm worker
    }
    sh_role = role;
  }
  __syncthreads();
  const int role = sh_role;

  if (role >= 0 && role < LBLK) {
    // =======================  LSTM role  =======================
    short* hl = (short*)smem;   // 32KB swizzled bf16 h

    const int blk = role;
    const int qb = blk * 64 + wid * 8;     // wave owns q in [qb, qb+8)
    unsigned* myflag = &wflag[(blk * 8 + wid) * 16];

    // ---- one-time: W A-frags, rows interleaved q*4+gate ----
    short8 wreg[2][16];
    #pragma unroll
    for (int mt = 0; mt < 2; ++mt) {
      const int qA = qb + mt * 4 + (fr >> 2);
      const int gA = fr & 3;
      const float* WgA = (gA == 0) ? Wf : (gA == 1) ? Wi : (gA == 2) ? Wo : Wc;
      const float* rowp = WgA + (size_t)qA * VH + V;
      #pragma unroll
      for (int kk = 0; kk < 16; ++kk) {
        const float4 lo = *(const float4*)(rowp + kk * 32 + ko * 8);
        const float4 hi = *(const float4*)(rowp + kk * 32 + ko * 8 + 4);
        short8 w;
        w[0] = (short)bf16_rne(lo.x); w[1] = (short)bf16_rne(lo.y);
        w[2] = (short)bf16_rne(lo.z); w[3] = (short)bf16_rne(lo.w);
        w[4] = (short)bf16_rne(hi.x); w[5] = (short)bf16_rne(hi.y);
        w[6] = (short)bf16_rne(hi.z); w[7] = (short)bf16_rne(hi.w);
        wreg[mt][kk] = w;
      }
    }

    // ---- c into VGPRs + h_init (slot 0) for own (b,q) pairs ----
    float creg[2][2];
    #pragma unroll
    for (int mt = 0; mt < 2; ++mt)
      #pragma unroll
      for (int nt = 0; nt < 2; ++nt) {
        const int b = nt * 16 + fr;
        const int q = qb + mt * 4 + rowgrp;
        creg[mt][nt] = Cin[b * HD + q];
        HsM1[(size_t)b * HD + q] = bf16_rne(Hin[b * HD + q]);
      }
    asm volatile("s_waitcnt vmcnt(0)" ::: "memory");   // slot-0 stores done
    if (lane == 0) astore(myflag, 1u);

    // E[0] after its gather flag
    while (aload(&eflag[0]) < 4u) {}
    f32x4 eldc[2][2];
    {
      const float* Eb0 = E;
      #pragma unroll
      for (int mt = 0; mt < 2; ++mt)
        #pragma unroll
        for (int nt = 0; nt < 2; ++nt) {
          const int b = nt * 16 + fr;
          const int q = qb + mt * 4 + rowgrp;
          eldc[mt][nt] = *(const f32x4*)(Eb0 + ((size_t)b * HD + q) * 4);
        }
    }

    const int bsw = (fr & 7) << 4;
    const int bbase0 = fr * 1024;
    const int bbase1 = (16 + fr) * 1024;

    for (int t = 0; t < TT; ++t) {
      // ---- poll: all 64 wave flags >= t+1; lane0 also gates E[t+1] ----
      {
        const unsigned* pa = &wflag[lane * 16];
        const unsigned need = (unsigned)(t + 1);
        const bool echk = (lane == 0) && (t + 1 < TT);
        while (true) {
          bool ok = aload(pa) >= need;
          if (echk) ok = ok && (aload(&eflag[t + 1]) >= 4u);
          if (__all((int)ok)) break;
        }
      }

      // ---- stage h slot t into LDS (XOR-swizzled source) ----
      const char* hsrc = (const char*)(HsM1 + (size_t)t * (BB * HD));
      #pragma unroll
      for (int is = 0; is < 4; ++is) {
        const int i = is * 512 + tid;
        const int sb = (i >> 6) * 1024 + (((i & 63) * 16) ^ (((i >> 6) & 7) << 4));
        gload_lds16(hsrc + sb, (char*)hl + (size_t)(is * 512 + (tid & ~63)) * 16);
      }
      __syncthreads();   // staging complete (vmcnt drain + barrier)

      // ---- MFMA P^T = W . h^T ----
      f32x4 acc[2][2];
      #pragma unroll
      for (int mt = 0; mt < 2; ++mt)
        #pragma unroll
        for (int nt = 0; nt < 2; ++nt)
          acc[mt][nt] = (f32x4){0.f, 0.f, 0.f, 0.f};
      #pragma unroll
      for (int kk = 0; kk < 16; ++kk) {
        const int off = kk * 64 + ko * 16;
        const short8 b0 = *(const short8*)((const char*)hl + bbase0 + (off ^ bsw));
        const short8 b1 = *(const short8*)((const char*)hl + bbase1 + (off ^ bsw));
        acc[0][0] = __builtin_amdgcn_mfma_f32_16x16x32_bf16(wreg[0][kk], b0, acc[0][0], 0, 0, 0);
        acc[0][1] = __builtin_amdgcn_mfma_f32_16x16x32_bf16(wreg[0][kk], b1, acc[0][1], 0, 0, 0);
        acc[1][0] = __builtin_amdgcn_mfma_f32_16x16x32_bf16(wreg[1][kk], b0, acc[1][0], 0, 0, 0);
        acc[1][1] = __builtin_amdgcn_mfma_f32_16x16x32_bf16(wreg[1][kk], b1, acc[1][1], 0, 0, 0);
      }

      // ---- in-lane gates (consume eldc); h store to slot t+1 ----
      unsigned short* hstore = HsM1 + (size_t)(t + 1) * (BB * HD);
      #pragma unroll
      for (int mt = 0; mt < 2; ++mt)
        #pragma unroll
        for (int nt = 0; nt < 2; ++nt) {
          const int b = nt * 16 + fr;
          const int q = qb + mt * 4 + rowgrp;
          const f32x4 a = acc[mt][nt];
          const f32x4 e4 = eldc[mt][nt];
          const float fg = sigf(a[0] + e4[0]);
          const float ig = sigf(a[1] + e4[1]);
          const float og = sigf(a[2] + e4[2]);
          const float ct = tanhf_fast(a[3] + e4[3]);
          const float cn = fg * creg[mt][nt] + ig * ct;
          const float hv = og * tanhf_fast(cn);
          creg[mt][nt] = cn;
          hstore[(size_t)b * HD + q] = bf16_rne(hv);
          if (t == TT - 1) {
            outHC[(size_t)b * HD + q] = hv;
            outHC[(size_t)BB * HD + b * HD + q] = cn;
          }
        }

      // drain ONLY the h stores (E loads for t+1 not yet issued), then flag
      asm volatile("s_waitcnt vmcnt(0)" ::: "memory");
      if (lane == 0) astore(myflag, (unsigned)(t + 2));

      // ---- E[t+1] load AFTER the flag: latency hides under next poll ----
      if (t + 1 < TT) {
        const float* Ebn = E + (size_t)(t + 1) * BB * HD * 4;
        #pragma unroll
        for (int mt = 0; mt < 2; ++mt)
          #pragma unroll
          for (int nt = 0; nt < 2; ++nt) {
            const int b = nt * 16 + fr;
            const int q = qb + mt * 4 + rowgrp;
            eldc[mt][nt] = *(const f32x4*)(Ebn + ((size_t)b * HD + q) * 4);
          }
      }
    }

    // ---- recurrence done: join the GEMM tile pool ----
    while (aload(wbar) < (unsigned)NGEMM)
      __builtin_amdgcn_s_sleep(8);
    __syncthreads();
    run_tiles(smem, Hs, Wyb, by, Y, bar2, tcount);

  } else if (role == 100) {
    // =======================  Publisher role (XCD0)  =======================
    if (wid == 0) {
      for (int T = 8; T <= TT; T += 8) {
        const unsigned need = (unsigned)(T + 1);
        while (true) {
          const unsigned v = aload(&wflag[lane * 16]);
          if (__all((int)(v >= need))) break;
          __builtin_amdgcn_s_sleep(2);
        }
        if (lane == 0) {
          __threadfence();            // wbl2: flush shared XCD0 L2 (h lines)
          astore(bar2, (unsigned)T);
        }
      }
    }
    __syncthreads();
    while (aload(wbar) < (unsigned)NGEMM)
      __builtin_amdgcn_s_sleep(8);
    __syncthreads();
    run_tiles(smem, Hs, Wyb, by, Y, bar2, tcount);

  } else {
    // =======================  GEMM worker role  =======================
    int* xs = (int*)(smem + 49152);
    const int gid = -role - 2;   // 0..NGEMM-1

    // ---- gather E quarter-chunks (u = t*4 + qtr, 8 b each) ----
    // NORMAL stores (not NT): E must live in L2/L3 so the lstm's per-step
    // E loads are cache hits, not HBM round-trips.
    for (int u = gid; u < 4 * TT; u += NGEMM) {
      const int tg = u >> 2, qtr = u & 3;
      if (tid < 8) xs[tid] = X[(qtr * 8 + tid) * TT + tg];
      __syncthreads();
      const int q = tid;
      const float b0v = bfp[q], b1v = bip[q], b2v = bop[q], b3v = bcp[q];
      float* Ebase = E + (size_t)tg * BB * HD * 4;
      #pragma unroll
      for (int b = 0; b < 8; ++b) {
        const int xv = xs[b];
        f32x4 ev;
        ev[0] = __builtin_nontemporal_load(Wf + (size_t)q * VH + xv) + b0v;
        ev[1] = __builtin_nontemporal_load(Wi + (size_t)q * VH + xv) + b1v;
        ev[2] = __builtin_nontemporal_load(Wo + (size_t)q * VH + xv) + b2v;
        ev[3] = __builtin_nontemporal_load(Wc + (size_t)q * VH + xv) + b3v;
        *(f32x4*)(Ebase + ((size_t)(qtr * 8 + b) * HD + q) * 4) = ev;
      }
      __syncthreads();
      if (tid == 0) {
        __threadfence();           // release E quarter (cross-XCD consumer)
        aadd(&eflag[tg], 1u);
      }
    }

    // ---- convert Wy -> Wyb (grid-stride) ----
    {
      const size_t n = (size_t)V * HD;
      for (size_t i = ((size_t)gid * 512 + tid) * 8; i < n;
           i += (size_t)NGEMM * 512 * 8) {
        const f32x4 a = __builtin_nontemporal_load((const f32x4*)(Wy + i));
        const f32x4 b = __builtin_nontemporal_load((const f32x4*)(Wy + i + 4));
        u16x8 o;
        o[0] = bf16_rne(a[0]); o[1] = bf16_rne(a[1]); o[2] = bf16_rne(a[2]); o[3] = bf16_rne(a[3]);
        o[4] = bf16_rne(b[0]); o[5] = bf16_rne(b[1]); o[6] = bf16_rne(b[2]); o[7] = bf16_rne(b[3]);
        *(u16x8*)(Wyb + i) = o;
      }
      __syncthreads();
      if (tid == 0) {
        __threadfence();
        aadd(wbar, 1u);
        while (aload(wbar) < (unsigned)NGEMM)
          __builtin_amdgcn_s_sleep(2);
      }
      __syncthreads();
    }

    run_tiles(smem, Hs, Wyb, by, Y, bar2, tcount);
  }
}

// ---------------------------------------------------------------------------
extern "C" void kernel_launch(void* const* d_in, const int* in_sizes, int n_in,
                              void* d_out, int out_size, void* d_ws, size_t ws_size,
                              hipStream_t stream)
{
  const int*   X  = (const int*)  d_in[0];
  const float* H  = (const float*)d_in[1];
  const float* C  = (const float*)d_in[2];
  const float* Wf = (const float*)d_in[3];
  const float* bf = (const float*)d_in[4];
  const float* Wi = (const float*)d_in[5];
  const float* bi = (const float*)d_in[6];
  const float* Wo = (const float*)d_in[7];
  const float* bo = (const float*)d_in[8];
  const float* Wc = (const float*)d_in[9];
  const float* bc = (const float*)d_in[10];
  const float* Wy = (const float*)d_in[11];
  const float* by = (const float*)d_in[12];

  float* Y = (float*)d_out;
  float* outHC = Y + (size_t)TT * BB * V;

  char* ws = (char*)d_ws;
  float* E              = (float*)ws;                               // 33,554,432 B
  unsigned short* Wyb   = (unsigned short*)(ws + 33554432);         // 32,768,000 B
  unsigned short* HsM1  = (unsigned short*)(ws + 66322432);         // 4,227,072 B
  char* ctrl            = ws + 70549504;
  unsigned* lticket     = (unsigned*)(ctrl + 0);
  unsigned* gticket     = (unsigned*)(ctrl + 64);
  unsigned* bar2        = (unsigned*)(ctrl + 128);
  unsigned* wbar        = (unsigned*)(ctrl + 192);
  unsigned* tcount      = (unsigned*)(ctrl + 256);
  unsigned* eflag       = (unsigned*)(ctrl + 320);    // 128 x 4B
  unsigned* wflag       = (unsigned*)(ctrl + 1024);   // 64 x 64B

  (void)hipMemsetAsync(ctrl, 0, 6144, stream);

  {
    const int* X_p = X;
    const float *H_p = H, *C_p = C;
    const float *Wf_p = Wf, *bf_p = bf, *Wi_p = Wi, *bi_p = bi;
    const float *Wo_p = Wo, *bo_p = bo, *Wc_p = Wc, *bc_p = bc;
    const float *Wy_p = Wy, *by_p = by;
    float* E_p = E;
    unsigned short* HsM1_p = HsM1;
    unsigned short* Wyb_p = Wyb;
    float* outHC_p = outHC;
    unsigned *bar2_p = bar2, *wbar_p = wbar, *tcount_p = tcount;
    unsigned *eflag_p = eflag, *wflag_p = wflag;
    unsigned *lticket_p = lticket, *gticket_p = gticket;
    float* Y_p = Y;
    void* args[] = {(void*)&X_p, (void*)&H_p, (void*)&C_p,
                    (void*)&Wf_p, (void*)&bf_p, (void*)&Wi_p, (void*)&bi_p,
                    (void*)&Wo_p, (void*)&bo_p, (void*)&Wc_p, (void*)&bc_p,
                    (void*)&Wy_p, (void*)&by_p,
                    (void*)&E_p, (void*)&HsM1_p, (void*)&Wyb_p, (void*)&outHC_p,
                    (void*)&bar2_p, (void*)&wbar_p, (void*)&tcount_p,
                    (void*)&eflag_p, (void*)&wflag_p,
                    (void*)&lticket_p, (void*)&gticket_p,
                    (void*)&Y_p};
    (void)hipLaunchCooperativeKernel((void*)fused_all, dim3(NBLK), dim3(512), args, 0, stream);
  }
}

// Round 12
// 933.644 us; speedup vs baseline: 1.0113x; 1.0113x over previous
//
#include <hip/hip_runtime.h>
#include <hip/hip_bf16.h>

#define V  32000
#define HD 512
#define BB 32
#define TT 128
#define VH 32512   // V + HD
#define LBLK 8     // lstm blocks (co-XCD0, weights register-resident)
#define NBLK 256   // total co-resident blocks (1 per CU)
#define NGEMM (NBLK - LBLK - 1)   // 247 gemm workers (1 publisher)
#define NTILE (32 * 125)          // gemm tiles: 4096/128 x 32000/256

typedef short  short8  __attribute__((ext_vector_type(8)));
typedef unsigned short u16x8 __attribute__((ext_vector_type(8)));
typedef unsigned short u16x4 __attribute__((ext_vector_type(4)));
typedef float  f32x4   __attribute__((ext_vector_type(4)));

__device__ __forceinline__ unsigned short bf16_rne(float f) {
  unsigned u = __builtin_bit_cast(unsigned, f);
  u += 0x7FFFu + ((u >> 16) & 1u);
  return (unsigned short)(u >> 16);
}

__device__ __forceinline__ void gload_lds16(const void* g, void* l) {
  __builtin_amdgcn_global_load_lds((const __attribute__((address_space(1))) void*)g,
                                   (__attribute__((address_space(3))) void*)l, 16, 0, 0);
}

__device__ __forceinline__ float sigf(float x) {
  return 1.0f / (1.0f + __expf(-x));
}
__device__ __forceinline__ float tanhf_fast(float x) {
  return 1.0f - 2.0f / (1.0f + __expf(2.0f * x));
}

__device__ __forceinline__ unsigned aload(const unsigned* p) {
  return __hip_atomic_load(p, __ATOMIC_RELAXED, __HIP_MEMORY_SCOPE_AGENT);
}
__device__ __forceinline__ void astore(unsigned* p, unsigned v) {
  __hip_atomic_store(p, v, __ATOMIC_RELAXED, __HIP_MEMORY_SCOPE_AGENT);
}
__device__ __forceinline__ unsigned aadd(unsigned* p, unsigned v) {
  return __hip_atomic_fetch_add(p, v, __ATOMIC_RELAXED, __HIP_MEMORY_SCOPE_AGENT);
}

// ---------------------------------------------------------------------------
// Persistent 128x256 GEMM tile loop, dynamic tile counter.
// ---------------------------------------------------------------------------
__device__ __forceinline__ void run_tiles(
    char* smem, const unsigned short* Hs, const unsigned short* Wyb,
    const float* by, float* Y, unsigned* bar2, unsigned* tcount)
{
  const int tid = threadIdx.x;
  const int wid = tid >> 6, lane = tid & 63;
  const int fr = lane & 15, ko = lane >> 4;
  const int wr = wid >> 2, wc = wid & 3;   // 2 x 4 wave grid
  unsigned short* As = (unsigned short*)smem;             // 128x64
  unsigned short* Bs = (unsigned short*)(smem + 16384);   // 256x64
  int* sh_tile = (int*)(smem + 49216);

  while (true) {
    if (tid == 0) *sh_tile = (int)aadd(tcount, 1u);
    __syncthreads();
    const int tile = *sh_tile;
    if (tile >= NTILE) break;
    const int bm = tile / 125, bn = tile % 125;
    const int row0 = bm << 7, col0 = bn << 8;

    if (tid == 0) {
      const unsigned need = (unsigned)(4 * bm + 4);
      while (aload(bar2) < need)
        __builtin_amdgcn_s_sleep(2);
    }
    __syncthreads();

    f32x4 acc[4][4];
    #pragma unroll
    for (int m = 0; m < 4; ++m)
      #pragma unroll
      for (int n = 0; n < 4; ++n)
        acc[m][n] = (f32x4){0.f, 0.f, 0.f, 0.f};

    for (int kt = 0; kt < 8; ++kt) {
      const int k0 = kt << 6;
      #pragma unroll
      for (int is = 0; is < 2; ++is) {
        const int id = is * 512 + tid;
        const int r = id >> 3;
        const int c = (id & 7) ^ (r & 7);
        gload_lds16(Hs + (size_t)(row0 + r) * 512 + k0 + c * 8,
                    &As[(is * 512 + (tid & ~63)) * 8]);
      }
      #pragma unroll
      for (int is = 0; is < 4; ++is) {
        const int id = is * 512 + tid;
        const int r = id >> 3;
        const int c = (id & 7) ^ (r & 7);
        gload_lds16(Wyb + (size_t)(col0 + r) * 512 + k0 + c * 8,
                    &Bs[(is * 512 + (tid & ~63)) * 8]);
      }
      __syncthreads();
      #pragma unroll
      for (int kk = 0; kk < 2; ++kk) {
        short8 af[4], bfr[4];
        #pragma unroll
        for (int m = 0; m < 4; ++m) {
          const int r = (wr << 6) + (m << 4) + fr;
          const int c = ((kk << 2) | ko) ^ (r & 7);
          af[m] = *(const short8*)&As[r * 64 + c * 8];
        }
        #pragma unroll
        for (int n = 0; n < 4; ++n) {
          const int r = (wc << 6) + (n << 4) + fr;
          const int c = ((kk << 2) | ko) ^ (r & 7);
          bfr[n] = *(const short8*)&Bs[r * 64 + c * 8];
        }
        #pragma unroll
        for (int m = 0; m < 4; ++m)
          #pragma unroll
          for (int n = 0; n < 4; ++n)
            acc[m][n] = __builtin_amdgcn_mfma_f32_16x16x32_bf16(
                af[m], bfr[n], acc[m][n], 0, 0, 0);
      }
      __syncthreads();
    }

    const int rgrp = lane >> 4;
    #pragma unroll
    for (int n = 0; n < 4; ++n) {
      const int col = col0 + (wc << 6) + (n << 4) + fr;
      const float bias = by[col];
      #pragma unroll
      for (int m = 0; m < 4; ++m) {
        const int rowb = row0 + (wr << 6) + (m << 4) + (rgrp << 2);
        #pragma unroll
        for (int j = 0; j < 4; ++j) {
          __builtin_nontemporal_store(acc[m][n][j] + bias,
                                      &Y[(size_t)(rowb + j) * V + col]);
        }
      }
    }
  }
}

// ---------------------------------------------------------------------------
// Fused cooperative kernel: 256 blocks x 512 threads.
// LDS = 81920 B > 160KB/2  =>  EXACTLY ONE BLOCK PER CU (no co-location:
// lstm blocks must own their CU; sharing with a GEMM block doubles step time).
// LSTM (8 XCD0 blocks): per-wave flags; poll -> stage h -> MFMA
//   (P^T = W.h^T, A-rows q*4+gate) -> in-lane gates -> h store -> vmcnt(0)
//   -> flag -> E[t+1] loads (off-path).
// Publisher (1 XCD0 block): polls wave flags, __threadfence + bar2 per 8
//   steps. GEMM workers (247): gather E ([t][q][b][4], coalesced for lstm),
//   convert Wyb, dynamic tiles.
// ---------------------------------------------------------------------------
__global__ void __launch_bounds__(512, 2) fused_all(
    const int* __restrict__ X,
    const float* __restrict__ Hin,
    const float* __restrict__ Cin,
    const float* __restrict__ Wf, const float* __restrict__ bfp,
    const float* __restrict__ Wi, const float* __restrict__ bip,
    const float* __restrict__ Wo, const float* __restrict__ bop,
    const float* __restrict__ Wc, const float* __restrict__ bcp,
    const float* __restrict__ Wy, const float* __restrict__ by,
    float* __restrict__ E,               // [TT][HD][BB][4] f32
    unsigned short* __restrict__ HsM1,   // slots 0..128: [129][32][512] bf16
    unsigned short* __restrict__ Wyb,    // [32000][512] bf16
    float* __restrict__ outHC,
    unsigned* __restrict__ bar2,
    unsigned* __restrict__ wbar,
    unsigned* __restrict__ tcount,
    unsigned* __restrict__ eflag,        // [TT] gather completion (4 each)
    unsigned* __restrict__ wflag,        // [64] per-wave flags, 64B apart
    unsigned* __restrict__ lticket,
    unsigned* __restrict__ gticket,
    float* __restrict__ Y)
{
  __shared__ __align__(16) char smem[81920];   // > 160KB/2: forces 1 block/CU
  __shared__ int sh_role;

  const int tid = threadIdx.x;
  const int wid = tid >> 6, lane = tid & 63;
  const int fr = lane & 15, ko = lane >> 4;
  const int rowgrp = lane >> 4;

  unsigned short* Hs = HsM1 + BB * HD;   // GEMM A view: slots 1..128

  // ---- runtime role claim on XCD0: 8 lstm + 1 publisher ----
  if (tid == 0) {
    unsigned xcd;
    asm volatile("s_getreg_b32 %0, hwreg(20, 0, 32)" : "=s"(xcd));  // XCC_ID
    int role = -1;
    if (xcd == 0) {
      const unsigned s = aadd(lticket, 1u);
      if (s < (unsigned)LBLK) role = (int)s;       // lstm 0..7
      else if (s == (unsigned)LBLK) role = 100;    // publisher
    }
    if (role == -1) {
      const unsigned g = aadd(gticket, 1u);
      role = -(int)g - 2;                          // gemm worker
    }
    sh_role = role;
  }
  __syncthreads();
  const int role = sh_role;

  if (role >= 0 && role < LBLK) {
    // =======================  LSTM role  =======================
    short* hl = (short*)smem;   // 32KB swizzled bf16 h

    const int blk = role;
    const int qb = blk * 64 + wid * 8;     // wave owns q in [qb, qb+8)
    unsigned* myflag = &wflag[(blk * 8 + wid) * 16];

    // ---- one-time: W A-frags, rows interleaved q*4+gate ----
    short8 wreg[2][16];
    #pragma unroll
    for (int mt = 0; mt < 2; ++mt) {
      const int qA = qb + mt * 4 + (fr >> 2);
      const int gA = fr & 3;
      const float* WgA = (gA == 0) ? Wf : (gA == 1) ? Wi : (gA == 2) ? Wo : Wc;
      const float* rowp = WgA + (size_t)qA * VH + V;
      #pragma unroll
      for (int kk = 0; kk < 16; ++kk) {
        const float4 lo = *(const float4*)(rowp + kk * 32 + ko * 8);
        const float4 hi = *(const float4*)(rowp + kk * 32 + ko * 8 + 4);
        short8 w;
        w[0] = (short)bf16_rne(lo.x); w[1] = (short)bf16_rne(lo.y);
        w[2] = (short)bf16_rne(lo.z); w[3] = (short)bf16_rne(lo.w);
        w[4] = (short)bf16_rne(hi.x); w[5] = (short)bf16_rne(hi.y);
        w[6] = (short)bf16_rne(hi.z); w[7] = (short)bf16_rne(hi.w);
        wreg[mt][kk] = w;
      }
    }

    // ---- c into VGPRs + h_init (slot 0) for own (b,q) pairs ----
    float creg[2][2];
    #pragma unroll
    for (int mt = 0; mt < 2; ++mt)
      #pragma unroll
      for (int nt = 0; nt < 2; ++nt) {
        const int b = nt * 16 + fr;
        const int q = qb + mt * 4 + rowgrp;
        creg[mt][nt] = Cin[b * HD + q];
        HsM1[(size_t)b * HD + q] = bf16_rne(Hin[b * HD + q]);
      }
    asm volatile("s_waitcnt vmcnt(0)" ::: "memory");   // slot-0 stores done
    if (lane == 0) astore(myflag, 1u);

    // E[0] after its gather flag
    while (aload(&eflag[0]) < 4u) {}
    f32x4 eldc[2][2];
    {
      const float* Eb0 = E;
      #pragma unroll
      for (int mt = 0; mt < 2; ++mt)
        #pragma unroll
        for (int nt = 0; nt < 2; ++nt) {
          const int b = nt * 16 + fr;
          const int q = qb + mt * 4 + rowgrp;
          eldc[mt][nt] = *(const f32x4*)(Eb0 + ((size_t)q * BB + b) * 4);
        }
    }

    const int bsw = (fr & 7) << 4;
    const int bbase0 = fr * 1024;
    const int bbase1 = (16 + fr) * 1024;

    for (int t = 0; t < TT; ++t) {
      // ---- poll: all 64 wave flags >= t+1; lane0 also gates E[t+1] ----
      {
        const unsigned* pa = &wflag[lane * 16];
        const unsigned need = (unsigned)(t + 1);
        const bool echk = (lane == 0) && (t + 1 < TT);
        while (true) {
          bool ok = aload(pa) >= need;
          if (echk) ok = ok && (aload(&eflag[t + 1]) >= 4u);
          if (__all((int)ok)) break;
        }
      }

      // ---- stage h slot t into LDS (XOR-swizzled source) ----
      const char* hsrc = (const char*)(HsM1 + (size_t)t * (BB * HD));
      #pragma unroll
      for (int is = 0; is < 4; ++is) {
        const int i = is * 512 + tid;
        const int sb = (i >> 6) * 1024 + (((i & 63) * 16) ^ (((i >> 6) & 7) << 4));
        gload_lds16(hsrc + sb, (char*)hl + (size_t)(is * 512 + (tid & ~63)) * 16);
      }
      __syncthreads();   // staging complete (vmcnt drain + barrier)

      // ---- MFMA P^T = W . h^T ----
      f32x4 acc[2][2];
      #pragma unroll
      for (int mt = 0; mt < 2; ++mt)
        #pragma unroll
        for (int nt = 0; nt < 2; ++nt)
          acc[mt][nt] = (f32x4){0.f, 0.f, 0.f, 0.f};
      #pragma unroll
      for (int kk = 0; kk < 16; ++kk) {
        const int off = kk * 64 + ko * 16;
        const short8 b0 = *(const short8*)((const char*)hl + bbase0 + (off ^ bsw));
        const short8 b1 = *(const short8*)((const char*)hl + bbase1 + (off ^ bsw));
        acc[0][0] = __builtin_amdgcn_mfma_f32_16x16x32_bf16(wreg[0][kk], b0, acc[0][0], 0, 0, 0);
        acc[0][1] = __builtin_amdgcn_mfma_f32_16x16x32_bf16(wreg[0][kk], b1, acc[0][1], 0, 0, 0);
        acc[1][0] = __builtin_amdgcn_mfma_f32_16x16x32_bf16(wreg[1][kk], b0, acc[1][0], 0, 0, 0);
        acc[1][1] = __builtin_amdgcn_mfma_f32_16x16x32_bf16(wreg[1][kk], b1, acc[1][1], 0, 0, 0);
      }

      // ---- in-lane gates (consume eldc); h store to slot t+1 ----
      unsigned short* hstore = HsM1 + (size_t)(t + 1) * (BB * HD);
      #pragma unroll
      for (int mt = 0; mt < 2; ++mt)
        #pragma unroll
        for (int nt = 0; nt < 2; ++nt) {
          const int b = nt * 16 + fr;
          const int q = qb + mt * 4 + rowgrp;
          const f32x4 a = acc[mt][nt];
          const f32x4 e4 = eldc[mt][nt];
          const float fg = sigf(a[0] + e4[0]);
          const float ig = sigf(a[1] + e4[1]);
          const float og = sigf(a[2] + e4[2]);
          const float ct = tanhf_fast(a[3] + e4[3]);
          const float cn = fg * creg[mt][nt] + ig * ct;
          const float hv = og * tanhf_fast(cn);
          creg[mt][nt] = cn;
          hstore[(size_t)b * HD + q] = bf16_rne(hv);
          if (t == TT - 1) {
            outHC[(size_t)b * HD + q] = hv;
            outHC[(size_t)BB * HD + b * HD + q] = cn;
          }
        }

      // drain ONLY the h stores (E loads for t+1 not yet issued), then flag
      asm volatile("s_waitcnt vmcnt(0)" ::: "memory");
      if (lane == 0) astore(myflag, (unsigned)(t + 2));

      // ---- E[t+1] load AFTER the flag: latency hides under next poll ----
      if (t + 1 < TT) {
        const float* Ebn = E + (size_t)(t + 1) * HD * BB * 4;
        #pragma unroll
        for (int mt = 0; mt < 2; ++mt)
          #pragma unroll
          for (int nt = 0; nt < 2; ++nt) {
            const int b = nt * 16 + fr;
            const int q = qb + mt * 4 + rowgrp;
            eldc[mt][nt] = *(const f32x4*)(Ebn + ((size_t)q * BB + b) * 4);
          }
      }
    }

    // ---- recurrence done: join the GEMM tile pool ----
    while (aload(wbar) < (unsigned)NGEMM)
      __builtin_amdgcn_s_sleep(8);
    __syncthreads();
    run_tiles(smem, Hs, Wyb, by, Y, bar2, tcount);

  } else if (role == 100) {
    // =======================  Publisher role (XCD0)  =======================
    if (wid == 0) {
      for (int T = 8; T <= TT; T += 8) {
        const unsigned need = (unsigned)(T + 1);
        while (true) {
          const unsigned v = aload(&wflag[lane * 16]);
          if (__all((int)(v >= need))) break;
          __builtin_amdgcn_s_sleep(2);
        }
        if (lane == 0) {
          __threadfence();            // wbl2: flush shared XCD0 L2 (h lines)
          astore(bar2, (unsigned)T);
        }
      }
    }
    __syncthreads();
    while (aload(wbar) < (unsigned)NGEMM)
      __builtin_amdgcn_s_sleep(8);
    __syncthreads();
    run_tiles(smem, Hs, Wyb, by, Y, bar2, tcount);

  } else {
    // =======================  GEMM worker role  =======================
    int* xs = (int*)(smem + 49152);
    const int gid = -role - 2;   // 0..NGEMM-1

    // ---- gather E quarter-chunks (u = t*4 + qtr, 8 b each) ----
    // E layout [t][q][b][4]: lstm reads 16 consecutive b per 16 lanes.
    for (int u = gid; u < 4 * TT; u += NGEMM) {
      const int tg = u >> 2, qtr = u & 3;
      if (tid < 8) xs[tid] = X[(qtr * 8 + tid) * TT + tg];
      __syncthreads();
      const int q = tid;
      const float b0v = bfp[q], b1v = bip[q], b2v = bop[q], b3v = bcp[q];
      float* Ebase = E + (size_t)tg * HD * BB * 4;
      #pragma unroll
      for (int b = 0; b < 8; ++b) {
        const int xv = xs[b];
        f32x4 ev;
        ev[0] = __builtin_nontemporal_load(Wf + (size_t)q * VH + xv) + b0v;
        ev[1] = __builtin_nontemporal_load(Wi + (size_t)q * VH + xv) + b1v;
        ev[2] = __builtin_nontemporal_load(Wo + (size_t)q * VH + xv) + b2v;
        ev[3] = __builtin_nontemporal_load(Wc + (size_t)q * VH + xv) + b3v;
        *(f32x4*)(Ebase + ((size_t)q * BB + qtr * 8 + b) * 4) = ev;
      }
      __syncthreads();
      if (tid == 0) {
        __threadfence();           // release E quarter (cross-XCD consumer)
        aadd(&eflag[tg], 1u);
      }
    }

    // ---- convert Wy -> Wyb (grid-stride) ----
    {
      const size_t n = (size_t)V * HD;
      for (size_t i = ((size_t)gid * 512 + tid) * 8; i < n;
           i += (size_t)NGEMM * 512 * 8) {
        const f32x4 a = __builtin_nontemporal_load((const f32x4*)(Wy + i));
        const f32x4 b = __builtin_nontemporal_load((const f32x4*)(Wy + i + 4));
        u16x8 o;
        o[0] = bf16_rne(a[0]); o[1] = bf16_rne(a[1]); o[2] = bf16_rne(a[2]); o[3] = bf16_rne(a[3]);
        o[4] = bf16_rne(b[0]); o[5] = bf16_rne(b[1]); o[6] = bf16_rne(b[2]); o[7] = bf16_rne(b[3]);
        *(u16x8*)(Wyb + i) = o;
      }
      __syncthreads();
      if (tid == 0) {
        __threadfence();
        aadd(wbar, 1u);
        while (aload(wbar) < (unsigned)NGEMM)
          __builtin_amdgcn_s_sleep(2);
      }
      __syncthreads();
    }

    run_tiles(smem, Hs, Wyb, by, Y, bar2, tcount);
  }
}

// ---------------------------------------------------------------------------
extern "C" void kernel_launch(void* const* d_in, const int* in_sizes, int n_in,
                              void* d_out, int out_size, void* d_ws, size_t ws_size,
                              hipStream_t stream)
{
  const int*   X  = (const int*)  d_in[0];
  const float* H  = (const float*)d_in[1];
  const float* C  = (const float*)d_in[2];
  const float* Wf = (const float*)d_in[3];
  const float* bf = (const float*)d_in[4];
  const float* Wi = (const float*)d_in[5];
  const float* bi = (const float*)d_in[6];
  const float* Wo = (const float*)d_in[7];
  const float* bo = (const float*)d_in[8];
  const float* Wc = (const float*)d_in[9];
  const float* bc = (const float*)d_in[10];
  const float* Wy = (const float*)d_in[11];
  const float* by = (const float*)d_in[12];

  float* Y = (float*)d_out;
  float* outHC = Y + (size_t)TT * BB * V;

  char* ws = (char*)d_ws;
  float* E              = (float*)ws;                               // 33,554,432 B
  unsigned short* Wyb   = (unsigned short*)(ws + 33554432);         // 32,768,000 B
  unsigned short* HsM1  = (unsigned short*)(ws + 66322432);         // 4,227,072 B
  char* ctrl            = ws + 70549504;
  unsigned* lticket     = (unsigned*)(ctrl + 0);
  unsigned* gticket     = (unsigned*)(ctrl + 64);
  unsigned* bar2        = (unsigned*)(ctrl + 128);
  unsigned* wbar        = (unsigned*)(ctrl + 192);
  unsigned* tcount      = (unsigned*)(ctrl + 256);
  unsigned* eflag       = (unsigned*)(ctrl + 320);    // 128 x 4B
  unsigned* wflag       = (unsigned*)(ctrl + 1024);   // 64 x 64B

  (void)hipMemsetAsync(ctrl, 0, 6144, stream);

  {
    const int* X_p = X;
    const float *H_p = H, *C_p = C;
    const float *Wf_p = Wf, *bf_p = bf, *Wi_p = Wi, *bi_p = bi;
    const float *Wo_p = Wo, *bo_p = bo, *Wc_p = Wc, *bc_p = bc;
    const float *Wy_p = Wy, *by_p = by;
    float* E_p = E;
    unsigned short* HsM1_p = HsM1;
    unsigned short* Wyb_p = Wyb;
    float* outHC_p = outHC;
    unsigned *bar2_p = bar2, *wbar_p = wbar, *tcount_p = tcount;
    unsigned *eflag_p = eflag, *wflag_p = wflag;
    unsigned *lticket_p = lticket, *gticket_p = gticket;
    float* Y_p = Y;
    void* args[] = {(void*)&X_p, (void*)&H_p, (void*)&C_p,
                    (void*)&Wf_p, (void*)&bf_p, (void*)&Wi_p, (void*)&bi_p,
                    (void*)&Wo_p, (void*)&bo_p, (void*)&Wc_p, (void*)&bc_p,
                    (void*)&Wy_p, (void*)&by_p,
                    (void*)&E_p, (void*)&HsM1_p, (void*)&Wyb_p, (void*)&outHC_p,
                    (void*)&bar2_p, (void*)&wbar_p, (void*)&tcount_p,
                    (void*)&eflag_p, (void*)&wflag_p,
                    (void*)&lticket_p, (void*)&gticket_p,
                    (void*)&Y_p};
    (void)hipLaunchCooperativeKernel((void*)fused_all, dim3(NBLK), dim3(512), args, 0, stream);
  }
}

// Round 14
// 866.827 us; speedup vs baseline: 1.0892x; 1.0771x over previous
//
#include <hip/hip_runtime.h>
#include <hip/hip_bf16.h>

#define V  32000
#define HD 512
#define BB 32
#define TT 128
#define VH 32512   // V + HD
#define LBLK 8     // lstm blocks (co-XCD0, weights register-resident)
#define NBLK 256   // total co-resident blocks (1 per CU)
#define NGEMM (NBLK - LBLK - 1)   // 247 gemm workers (1 publisher)
#define NTILE (32 * 125)          // gemm tiles: 4096/128 x 32000/256

typedef short  short8  __attribute__((ext_vector_type(8)));
typedef unsigned short u16x8 __attribute__((ext_vector_type(8)));
typedef unsigned short u16x4 __attribute__((ext_vector_type(4)));
typedef float  f32x4   __attribute__((ext_vector_type(4)));

__device__ __forceinline__ unsigned short bf16_rne(float f) {
  unsigned u = __builtin_bit_cast(unsigned, f);
  u += 0x7FFFu + ((u >> 16) & 1u);
  return (unsigned short)(u >> 16);
}

__device__ __forceinline__ void gload_lds16(const void* g, void* l) {
  __builtin_amdgcn_global_load_lds((const __attribute__((address_space(1))) void*)g,
                                   (__attribute__((address_space(3))) void*)l, 16, 0, 0);
}

__device__ __forceinline__ float sigf(float x) {
  return 1.0f / (1.0f + __expf(-x));
}
__device__ __forceinline__ float tanhf_fast(float x) {
  return 1.0f - 2.0f / (1.0f + __expf(2.0f * x));
}

__device__ __forceinline__ unsigned aload(const unsigned* p) {
  return __hip_atomic_load(p, __ATOMIC_RELAXED, __HIP_MEMORY_SCOPE_AGENT);
}
__device__ __forceinline__ void astore(unsigned* p, unsigned v) {
  __hip_atomic_store(p, v, __ATOMIC_RELAXED, __HIP_MEMORY_SCOPE_AGENT);
}
__device__ __forceinline__ unsigned aadd(unsigned* p, unsigned v) {
  return __hip_atomic_fetch_add(p, v, __ATOMIC_RELAXED, __HIP_MEMORY_SCOPE_AGENT);
}

// ---------------------------------------------------------------------------
// Persistent 128x256 GEMM tile loop, dynamic tile counter.
// ---------------------------------------------------------------------------
__device__ __forceinline__ void run_tiles(
    char* smem, const unsigned short* Hs, const unsigned short* Wyb,
    const float* by, float* Y, unsigned* bar2, unsigned* tcount)
{
  const int tid = threadIdx.x;
  const int wid = tid >> 6, lane = tid & 63;
  const int fr = lane & 15, ko = lane >> 4;
  const int wr = wid >> 2, wc = wid & 3;   // 2 x 4 wave grid
  unsigned short* As = (unsigned short*)smem;             // 128x64
  unsigned short* Bs = (unsigned short*)(smem + 16384);   // 256x64
  int* sh_tile = (int*)(smem + 49216);

  while (true) {
    if (tid == 0) *sh_tile = (int)aadd(tcount, 1u);
    __syncthreads();
    const int tile = *sh_tile;
    if (tile >= NTILE) break;
    const int bm = tile / 125, bn = tile % 125;
    const int row0 = bm << 7, col0 = bn << 8;

    if (tid == 0) {
      const unsigned need = (unsigned)(4 * bm + 4);
      while (aload(bar2) < need)
        __builtin_amdgcn_s_sleep(32);   // coarse poll: de-hotspot bar2 line
    }
    __syncthreads();

    f32x4 acc[4][4];
    #pragma unroll
    for (int m = 0; m < 4; ++m)
      #pragma unroll
      for (int n = 0; n < 4; ++n)
        acc[m][n] = (f32x4){0.f, 0.f, 0.f, 0.f};

    for (int kt = 0; kt < 8; ++kt) {
      const int k0 = kt << 6;
      #pragma unroll
      for (int is = 0; is < 2; ++is) {
        const int id = is * 512 + tid;
        const int r = id >> 3;
        const int c = (id & 7) ^ (r & 7);
        gload_lds16(Hs + (size_t)(row0 + r) * 512 + k0 + c * 8,
                    &As[(is * 512 + (tid & ~63)) * 8]);
      }
      #pragma unroll
      for (int is = 0; is < 4; ++is) {
        const int id = is * 512 + tid;
        const int r = id >> 3;
        const int c = (id & 7) ^ (r & 7);
        gload_lds16(Wyb + (size_t)(col0 + r) * 512 + k0 + c * 8,
                    &Bs[(is * 512 + (tid & ~63)) * 8]);
      }
      __syncthreads();
      #pragma unroll
      for (int kk = 0; kk < 2; ++kk) {
        short8 af[4], bfr[4];
        #pragma unroll
        for (int m = 0; m < 4; ++m) {
          const int r = (wr << 6) + (m << 4) + fr;
          const int c = ((kk << 2) | ko) ^ (r & 7);
          af[m] = *(const short8*)&As[r * 64 + c * 8];
        }
        #pragma unroll
        for (int n = 0; n < 4; ++n) {
          const int r = (wc << 6) + (n << 4) + fr;
          const int c = ((kk << 2) | ko) ^ (r & 7);
          bfr[n] = *(const short8*)&Bs[r * 64 + c * 8];
        }
        #pragma unroll
        for (int m = 0; m < 4; ++m)
          #pragma unroll
          for (int n = 0; n < 4; ++n)
            acc[m][n] = __builtin_amdgcn_mfma_f32_16x16x32_bf16(
                af[m], bfr[n], acc[m][n], 0, 0, 0);
      }
      __syncthreads();
    }

    const int rgrp = lane >> 4;
    #pragma unroll
    for (int n = 0; n < 4; ++n) {
      const int col = col0 + (wc << 6) + (n << 4) + fr;
      const float bias = by[col];
      #pragma unroll
      for (int m = 0; m < 4; ++m) {
        const int rowb = row0 + (wr << 6) + (m << 4) + (rgrp << 2);
        #pragma unroll
        for (int j = 0; j < 4; ++j) {
          __builtin_nontemporal_store(acc[m][n][j] + bias,
                                      &Y[(size_t)(rowb + j) * V + col]);
        }
      }
    }
  }
}

// ---------------------------------------------------------------------------
// Fused cooperative kernel: 256 blocks x 512 threads (1 per CU).
// LSTM (8 XCD0 blocks): per-wave agent flags; poll -> stage h -> E[t+1]
//   prefetch -> MFMA (P^T = W.h^T, A-rows q*4+gate) -> in-lane gates ->
//   h store -> vmcnt(0) -> flag.
// Publisher (1 XCD0 block): polls wave flags (agent), __threadfence + bar2
//   per 8 steps.
// GEMM workers (247): gather E quarters -> convert Wyb -> dynamic tiles.
//   XCD0-resident workers SLEEP during the recurrence (bar2 < TT) so the
//   lstm's shared L2 isn't thrashed by panel streams; they join for the tail.
// ---------------------------------------------------------------------------
__global__ void __launch_bounds__(512, 2) fused_all(
    const int* __restrict__ X,
    const float* __restrict__ Hin,
    const float* __restrict__ Cin,
    const float* __restrict__ Wf, const float* __restrict__ bfp,
    const float* __restrict__ Wi, const float* __restrict__ bip,
    const float* __restrict__ Wo, const float* __restrict__ bop,
    const float* __restrict__ Wc, const float* __restrict__ bcp,
    const float* __restrict__ Wy, const float* __restrict__ by,
    float* __restrict__ E,               // [TT][BB][HD][4] f32
    unsigned short* __restrict__ HsM1,   // slots 0..128: [129][32][512] bf16
    unsigned short* __restrict__ Wyb,    // [32000][512] bf16
    float* __restrict__ outHC,
    unsigned* __restrict__ bar2,
    unsigned* __restrict__ wbar,
    unsigned* __restrict__ tcount,
    unsigned* __restrict__ eflag,        // [TT] gather completion (4 each)
    unsigned* __restrict__ wflag,        // [64] per-wave flags, 64B apart
    unsigned* __restrict__ lticket,
    unsigned* __restrict__ gticket,
    float* __restrict__ Y)
{
  __shared__ __align__(16) char smem[75776];
  __shared__ int sh_role, sh_x0;

  const int tid = threadIdx.x;
  const int wid = tid >> 6, lane = tid & 63;
  const int fr = lane & 15, ko = lane >> 4;
  const int rowgrp = lane >> 4;

  unsigned short* Hs = HsM1 + BB * HD;   // GEMM A view: slots 1..128

  // ---- runtime role claim on XCD0: 8 lstm + 1 publisher ----
  if (tid == 0) {
    unsigned xcd;
    asm volatile("s_getreg_b32 %0, hwreg(20, 0, 32)" : "=s"(xcd));  // XCC_ID
    int role = -1;
    if (xcd == 0) {
      const unsigned s = aadd(lticket, 1u);
      if (s < (unsigned)LBLK) role = (int)s;       // lstm 0..7
      else if (s == (unsigned)LBLK) role = 100;    // publisher
    }
    if (role == -1) {
      const unsigned g = aadd(gticket, 1u);
      role = -(int)g - 2;                          // gemm worker
    }
    sh_role = role;
    sh_x0 = (xcd == 0) ? 1 : 0;
  }
  __syncthreads();
  const int role = sh_role;

  if (role >= 0 && role < LBLK) {
    // =======================  LSTM role  =======================
    short* hl = (short*)smem;   // 32KB swizzled bf16 h

    const int blk = role;
    const int qb = blk * 64 + wid * 8;     // wave owns q in [qb, qb+8)
    unsigned* myflag = &wflag[(blk * 8 + wid) * 16];

    // ---- one-time: W A-frags, rows interleaved q*4+gate ----
    short8 wreg[2][16];
    #pragma unroll
    for (int mt = 0; mt < 2; ++mt) {
      const int qA = qb + mt * 4 + (fr >> 2);
      const int gA = fr & 3;
      const float* WgA = (gA == 0) ? Wf : (gA == 1) ? Wi : (gA == 2) ? Wo : Wc;
      const float* rowp = WgA + (size_t)qA * VH + V;
      #pragma unroll
      for (int kk = 0; kk < 16; ++kk) {
        const float4 lo = *(const float4*)(rowp + kk * 32 + ko * 8);
        const float4 hi = *(const float4*)(rowp + kk * 32 + ko * 8 + 4);
        short8 w;
        w[0] = (short)bf16_rne(lo.x); w[1] = (short)bf16_rne(lo.y);
        w[2] = (short)bf16_rne(lo.z); w[3] = (short)bf16_rne(lo.w);
        w[4] = (short)bf16_rne(hi.x); w[5] = (short)bf16_rne(hi.y);
        w[6] = (short)bf16_rne(hi.z); w[7] = (short)bf16_rne(hi.w);
        wreg[mt][kk] = w;
      }
    }

    // ---- c into VGPRs + h_init (slot 0) for own (b,q) pairs ----
    float creg[2][2];
    #pragma unroll
    for (int mt = 0; mt < 2; ++mt)
      #pragma unroll
      for (int nt = 0; nt < 2; ++nt) {
        const int b = nt * 16 + fr;
        const int q = qb + mt * 4 + rowgrp;
        creg[mt][nt] = Cin[b * HD + q];
        HsM1[(size_t)b * HD + q] = bf16_rne(Hin[b * HD + q]);
      }
    asm volatile("s_waitcnt vmcnt(0)" ::: "memory");   // slot-0 stores done
    if (lane == 0) astore(myflag, 1u);

    // E[0] after its gather flag
    while (aload(&eflag[0]) < 4u) {}
    f32x4 eldc[2][2];
    {
      const float* Eb0 = E;
      #pragma unroll
      for (int mt = 0; mt < 2; ++mt)
        #pragma unroll
        for (int nt = 0; nt < 2; ++nt) {
          const int b = nt * 16 + fr;
          const int q = qb + mt * 4 + rowgrp;
          eldc[mt][nt] = *(const f32x4*)(Eb0 + ((size_t)b * HD + q) * 4);
        }
    }

    const int bsw = (fr & 7) << 4;
    const int bbase0 = fr * 1024;
    const int bbase1 = (16 + fr) * 1024;

    for (int t = 0; t < TT; ++t) {
      // ---- poll: all 64 wave flags >= t+1; lane0 also gates E[t+1] ----
      {
        const unsigned* pa = &wflag[lane * 16];
        const unsigned need = (unsigned)(t + 1);
        const bool echk = (lane == 0) && (t + 1 < TT);
        while (true) {
          bool ok = aload(pa) >= need;
          if (echk) ok = ok && (aload(&eflag[t + 1]) >= 4u);
          if (__all((int)ok)) break;
        }
      }

      // ---- stage h slot t into LDS (XOR-swizzled source) ----
      const char* hsrc = (const char*)(HsM1 + (size_t)t * (BB * HD));
      #pragma unroll
      for (int is = 0; is < 4; ++is) {
        const int i = is * 512 + tid;
        const int sb = (i >> 6) * 1024 + (((i & 63) * 16) ^ (((i >> 6) & 7) << 4));
        gload_lds16(hsrc + sb, (char*)hl + (size_t)(is * 512 + (tid & ~63)) * 16);
      }
      __syncthreads();   // staging complete (vmcnt drain + barrier)

      // ---- E[t+1] prefetch (off critical path, consumed next step) ----
      f32x4 eldn[2][2];
      if (t + 1 < TT) {
        const float* Ebn = E + (size_t)(t + 1) * BB * HD * 4;
        #pragma unroll
        for (int mt = 0; mt < 2; ++mt)
          #pragma unroll
          for (int nt = 0; nt < 2; ++nt) {
            const int b = nt * 16 + fr;
            const int q = qb + mt * 4 + rowgrp;
            eldn[mt][nt] = *(const f32x4*)(Ebn + ((size_t)b * HD + q) * 4);
          }
      }

      // ---- MFMA P^T = W . h^T ----
      f32x4 acc[2][2];
      #pragma unroll
      for (int mt = 0; mt < 2; ++mt)
        #pragma unroll
        for (int nt = 0; nt < 2; ++nt)
          acc[mt][nt] = (f32x4){0.f, 0.f, 0.f, 0.f};
      #pragma unroll
      for (int kk = 0; kk < 16; ++kk) {
        const int off = kk * 64 + ko * 16;
        const short8 b0 = *(const short8*)((const char*)hl + bbase0 + (off ^ bsw));
        const short8 b1 = *(const short8*)((const char*)hl + bbase1 + (off ^ bsw));
        acc[0][0] = __builtin_amdgcn_mfma_f32_16x16x32_bf16(wreg[0][kk], b0, acc[0][0], 0, 0, 0);
        acc[0][1] = __builtin_amdgcn_mfma_f32_16x16x32_bf16(wreg[0][kk], b1, acc[0][1], 0, 0, 0);
        acc[1][0] = __builtin_amdgcn_mfma_f32_16x16x32_bf16(wreg[1][kk], b0, acc[1][0], 0, 0, 0);
        acc[1][1] = __builtin_amdgcn_mfma_f32_16x16x32_bf16(wreg[1][kk], b1, acc[1][1], 0, 0, 0);
      }

      // ---- in-lane gates; h store to slot t+1 ----
      unsigned short* hstore = HsM1 + (size_t)(t + 1) * (BB * HD);
      #pragma unroll
      for (int mt = 0; mt < 2; ++mt)
        #pragma unroll
        for (int nt = 0; nt < 2; ++nt) {
          const int b = nt * 16 + fr;
          const int q = qb + mt * 4 + rowgrp;
          const f32x4 a = acc[mt][nt];
          const f32x4 e4 = eldc[mt][nt];
          const float fg = sigf(a[0] + e4[0]);
          const float ig = sigf(a[1] + e4[1]);
          const float og = sigf(a[2] + e4[2]);
          const float ct = tanhf_fast(a[3] + e4[3]);
          const float cn = fg * creg[mt][nt] + ig * ct;
          const float hv = og * tanhf_fast(cn);
          creg[mt][nt] = cn;
          hstore[(size_t)b * HD + q] = bf16_rne(hv);
          if (t == TT - 1) {
            outHC[(size_t)b * HD + q] = hv;
            outHC[(size_t)BB * HD + b * HD + q] = cn;
          }
        }

      asm volatile("s_waitcnt vmcnt(0)" ::: "memory");   // h stores in L2
      if (lane == 0) astore(myflag, (unsigned)(t + 2));

      #pragma unroll
      for (int mt = 0; mt < 2; ++mt)
        #pragma unroll
        for (int nt = 0; nt < 2; ++nt)
          eldc[mt][nt] = eldn[mt][nt];
    }

    // ---- recurrence done: join the GEMM tile pool ----
    while (aload(wbar) < (unsigned)NGEMM)
      __builtin_amdgcn_s_sleep(8);
    __syncthreads();
    run_tiles(smem, Hs, Wyb, by, Y, bar2, tcount);

  } else if (role == 100) {
    // =======================  Publisher role (XCD0)  =======================
    if (wid == 0) {
      for (int T = 8; T <= TT; T += 8) {
        const unsigned need = (unsigned)(T + 1);
        while (true) {
          const unsigned v = aload(&wflag[lane * 16]);
          if (__all((int)(v >= need))) break;
          __builtin_amdgcn_s_sleep(2);
        }
        if (lane == 0) {
          __threadfence();            // wbl2: flush shared XCD0 L2 (h lines)
          astore(bar2, (unsigned)T);
        }
      }
    }
    __syncthreads();
    while (aload(wbar) < (unsigned)NGEMM)
      __builtin_amdgcn_s_sleep(8);
    __syncthreads();
    run_tiles(smem, Hs, Wyb, by, Y, bar2, tcount);

  } else {
    // =======================  GEMM worker role  =======================
    int* xs = (int*)(smem + 49152);
    const int gid = -role - 2;   // 0..NGEMM-1
    const int x0 = sh_x0;

    // ---- gather E quarter-chunks (u = t*4 + qtr, 8 b each) ----
    for (int u = gid; u < 4 * TT; u += NGEMM) {
      const int tg = u >> 2, qtr = u & 3;
      if (tid < 8) xs[tid] = X[(qtr * 8 + tid) * TT + tg];
      __syncthreads();
      const int q = tid;
      const float b0v = bfp[q], b1v = bip[q], b2v = bop[q], b3v = bcp[q];
      float* Ebase = E + (size_t)tg * BB * HD * 4;
      #pragma unroll
      for (int b = 0; b < 8; ++b) {
        const int xv = xs[b];
        f32x4 ev;
        ev[0] = __builtin_nontemporal_load(Wf + (size_t)q * VH + xv) + b0v;
        ev[1] = __builtin_nontemporal_load(Wi + (size_t)q * VH + xv) + b1v;
        ev[2] = __builtin_nontemporal_load(Wo + (size_t)q * VH + xv) + b2v;
        ev[3] = __builtin_nontemporal_load(Wc + (size_t)q * VH + xv) + b3v;
        __builtin_nontemporal_store(ev,
            (f32x4*)(Ebase + ((size_t)(qtr * 8 + b) * HD + q) * 4));
      }
      __syncthreads();
      if (tid == 0) {
        __threadfence();           // release E quarter (cross-XCD consumer)
        aadd(&eflag[tg], 1u);
      }
    }

    // ---- convert Wy -> Wyb (grid-stride) ----
    {
      const size_t n = (size_t)V * HD;
      for (size_t i = ((size_t)gid * 512 + tid) * 8; i < n;
           i += (size_t)NGEMM * 512 * 8) {
        const f32x4 a = __builtin_nontemporal_load((const f32x4*)(Wy + i));
        const f32x4 b = __builtin_nontemporal_load((const f32x4*)(Wy + i + 4));
        u16x8 o;
        o[0] = bf16_rne(a[0]); o[1] = bf16_rne(a[1]); o[2] = bf16_rne(a[2]); o[3] = bf16_rne(a[3]);
        o[4] = bf16_rne(b[0]); o[5] = bf16_rne(b[1]); o[6] = bf16_rne(b[2]); o[7] = bf16_rne(b[3]);
        *(u16x8*)(Wyb + i) = o;
      }
      __syncthreads();
      if (tid == 0) {
        __threadfence();
        aadd(wbar, 1u);
        while (aload(wbar) < (unsigned)NGEMM)
          __builtin_amdgcn_s_sleep(2);
      }
      __syncthreads();
    }

    // XCD0 workers: keep the lstm's shared L2 quiet during the recurrence;
    // join the tile pool once the recurrence has finished.
    if (x0) {
      if (tid == 0) {
        while (aload(bar2) < (unsigned)TT)
          __builtin_amdgcn_s_sleep(64);
      }
      __syncthreads();
    }

    run_tiles(smem, Hs, Wyb, by, Y, bar2, tcount);
  }
}

// ---------------------------------------------------------------------------
extern "C" void kernel_launch(void* const* d_in, const int* in_sizes, int n_in,
                              void* d_out, int out_size, void* d_ws, size_t ws_size,
                              hipStream_t stream)
{
  const int*   X  = (const int*)  d_in[0];
  const float* H  = (const float*)d_in[1];
  const float* C  = (const float*)d_in[2];
  const float* Wf = (const float*)d_in[3];
  const float* bf = (const float*)d_in[4];
  const float* Wi = (const float*)d_in[5];
  const float* bi = (const float*)d_in[6];
  const float* Wo = (const float*)d_in[7];
  const float* bo = (const float*)d_in[8];
  const float* Wc = (const float*)d_in[9];
  const float* bc = (const float*)d_in[10];
  const float* Wy = (const float*)d_in[11];
  const float* by = (const float*)d_in[12];

  float* Y = (float*)d_out;
  float* outHC = Y + (size_t)TT * BB * V;

  char* ws = (char*)d_ws;
  float* E              = (float*)ws;                               // 33,554,432 B
  unsigned short* Wyb   = (unsigned short*)(ws + 33554432);         // 32,768,000 B
  unsigned short* HsM1  = (unsigned short*)(ws + 66322432);         // 4,227,072 B
  char* ctrl            = ws + 70549504;
  unsigned* lticket     = (unsigned*)(ctrl + 0);
  unsigned* gticket     = (unsigned*)(ctrl + 64);
  unsigned* bar2        = (unsigned*)(ctrl + 128);
  unsigned* wbar        = (unsigned*)(ctrl + 192);
  unsigned* tcount      = (unsigned*)(ctrl + 256);
  unsigned* eflag       = (unsigned*)(ctrl + 320);    // 128 x 4B
  unsigned* wflag       = (unsigned*)(ctrl + 1024);   // 64 x 64B

  (void)hipMemsetAsync(ctrl, 0, 6144, stream);

  {
    const int* X_p = X;
    const float *H_p = H, *C_p = C;
    const float *Wf_p = Wf, *bf_p = bf, *Wi_p = Wi, *bi_p = bi;
    const float *Wo_p = Wo, *bo_p = bo, *Wc_p = Wc, *bc_p = bc;
    const float *Wy_p = Wy, *by_p = by;
    float* E_p = E;
    unsigned short* HsM1_p = HsM1;
    unsigned short* Wyb_p = Wyb;
    float* outHC_p = outHC;
    unsigned *bar2_p = bar2, *wbar_p = wbar, *tcount_p = tcount;
    unsigned *eflag_p = eflag, *wflag_p = wflag;
    unsigned *lticket_p = lticket, *gticket_p = gticket;
    float* Y_p = Y;
    void* args[] = {(void*)&X_p, (void*)&H_p, (void*)&C_p,
                    (void*)&Wf_p, (void*)&bf_p, (void*)&Wi_p, (void*)&bi_p,
                    (void*)&Wo_p, (void*)&bo_p, (void*)&Wc_p, (void*)&bc_p,
                    (void*)&Wy_p, (void*)&by_p,
                    (void*)&E_p, (void*)&HsM1_p, (void*)&Wyb_p, (void*)&outHC_p,
                    (void*)&bar2_p, (void*)&wbar_p, (void*)&tcount_p,
                    (void*)&eflag_p, (void*)&wflag_p,
                    (void*)&lticket_p, (void*)&gticket_p,
                    (void*)&Y_p};
    (void)hipLaunchCooperativeKernel((void*)fused_all, dim3(NBLK), dim3(512), args, 0, stream);
  }
}